// Round 1
// baseline (125.737 us; speedup 1.0000x reference)
//
#include <hip/hip_runtime.h>
#include <stdint.h>

typedef __attribute__((ext_vector_type(8))) short bf16x8;
typedef __attribute__((ext_vector_type(4))) float f32x4;
typedef __attribute__((ext_vector_type(4))) int i32x4;

#define NH 128
#define NW 128
#define NC 64
#define NF 256
#define NKG 576   // 9 * 64

__device__ __forceinline__ unsigned short f2b(float f) {
  union { float f; uint32_t u; } t; t.f = f;
  uint32_t u = t.u;
  return (unsigned short)((u + 0x7fffu + ((u >> 16) & 1u)) >> 16);
}

// Transpose + convert kernel [576][256] f32 -> Bt [256][576] bf16 in ws.
__global__ void prep_bt(const float* __restrict__ kr, unsigned short* __restrict__ bt) {
  int idx = blockIdx.x * 256 + threadIdx.x;     // 147456 total
  int f = idx / NKG;
  int k = idx - f * NKG;
  bt[idx] = f2b(kr[k * NF + f]);
}

#define LDS_B_OFF (3 * 16384)

// LDS layout (all bf16, 16B-block XOR swizzle to avoid 128B-stride bank conflicts):
//  xbuf: 3 rows x [w=128][cb=8 blocks of 8ch]  addr = r*16384 + w*128 + ((cb^(w&7))<<4)
//  bbuf: 2 bufs x [n=128][kb=8]                addr = LDS_B_OFF + buf*16384 + n*128 + ((kb^(n&7))<<4)
__global__ __launch_bounds__(256, 2)
void conv_main(const float* __restrict__ x, const unsigned short* __restrict__ bt,
               const float* __restrict__ bias, float* __restrict__ out)
{
  __shared__ __align__(16) char lds[3 * 16384 + 2 * 16384];   // 80 KB

  const int tid  = threadIdx.x;
  const int lane = tid & 63;
  const int l15  = lane & 15;
  const int l4   = lane >> 4;
  const int wid  = tid >> 6;
  const int wm   = wid >> 1;    // wave row (2)
  const int wn   = wid & 1;     // wave col (2)

  // XCD-aware bijective swizzle: nwg=4096, 8 XCDs, 512 per XCD.
  int bid  = (int)blockIdx.x;
  int work = (bid & 7) * 512 + (bid >> 3);
  int mi = work >> 1;           // 0..2047 : (b,h) flat
  int fi = work & 1;            // F half
  int bb = mi >> 7;
  int hh = mi & 127;
  int F0 = fi * 128;

  // ---- stage A: x rows h-1,h,h+1 (circular) -> bf16 swizzled LDS, once ----
  #pragma unroll
  for (int i = 0; i < 12; ++i) {
    int idx = tid + i * 256;            // 3072 16B-blocks
    int cb = idx & 7;
    int w  = (idx >> 3) & 127;
    int r  = idx >> 10;                 // 0..2
    int xr = (hh + r - 1) & 127;
    const float* src = x + (((bb * NH + xr) * NW + w) * NC + cb * 8);
    float4 a0 = *(const float4*)(src);
    float4 a1 = *(const float4*)(src + 4);
    union { unsigned short u[8]; i32x4 v; } p;
    p.u[0] = f2b(a0.x); p.u[1] = f2b(a0.y); p.u[2] = f2b(a0.z); p.u[3] = f2b(a0.w);
    p.u[4] = f2b(a1.x); p.u[5] = f2b(a1.y); p.u[6] = f2b(a1.z); p.u[7] = f2b(a1.w);
    *(i32x4*)(lds + (r * 16384 + w * 128 + ((cb ^ (w & 7)) << 4))) = p.v;
  }

  // ---- stage B(shift 0) into buf0 ----
  #pragma unroll
  for (int i = 0; i < 4; ++i) {
    int idx = tid + i * 256;            // 1024 16B-blocks
    int kb = idx & 7;
    int n  = idx >> 3;
    i32x4 v = *(const i32x4*)(bt + ((F0 + n) * NKG + kb * 8));
    *(i32x4*)(lds + (LDS_B_OFF + n * 128 + ((kb ^ (n & 7)) << 4))) = v;
  }
  __syncthreads();

  f32x4 acc[4][4];
  #pragma unroll
  for (int m = 0; m < 4; ++m)
    #pragma unroll
    for (int n = 0; n < 4; ++n)
      acc[m][n] = (f32x4){0.f, 0.f, 0.f, 0.f};

  #pragma unroll
  for (int s = 0; s < 9; ++s) {
    const int cur = s & 1;
    if (s < 8) {  // prefetch next shift's B-tile into other buffer
      #pragma unroll
      for (int i = 0; i < 4; ++i) {
        int idx = tid + i * 256;
        int kb = idx & 7;
        int n  = idx >> 3;
        i32x4 v = *(const i32x4*)(bt + ((F0 + n) * NKG + (s + 1) * 64 + kb * 8));
        *(i32x4*)(lds + (LDS_B_OFF + (cur ^ 1) * 16384 + n * 128 + ((kb ^ (n & 7)) << 4))) = v;
      }
    }
    const int r  = 2 - (s % 3);     // which staged x-row
    const int dw = 1 - (s / 3);     // circular w offset
    const char* abase = lds + r * 16384;
    const char* bbase = lds + LDS_B_OFF + cur * 16384;
    #pragma unroll
    for (int kk = 0; kk < 2; ++kk) {
      bf16x8 af[4], bfv[4];
      const int kb = kk * 4 + l4;
      #pragma unroll
      for (int m = 0; m < 4; ++m) {
        int wsrc = (wm * 64 + m * 16 + l15 + dw) & 127;
        af[m] = *(const bf16x8*)(abase + wsrc * 128 + ((kb ^ (wsrc & 7)) << 4));
      }
      #pragma unroll
      for (int n = 0; n < 4; ++n) {
        int nr = wn * 64 + n * 16 + l15;
        bfv[n] = *(const bf16x8*)(bbase + nr * 128 + ((kb ^ (nr & 7)) << 4));
      }
      #pragma unroll
      for (int m = 0; m < 4; ++m)
        #pragma unroll
        for (int n = 0; n < 4; ++n)
          acc[m][n] = __builtin_amdgcn_mfma_f32_16x16x32_bf16(af[m], bfv[n], acc[m][n], 0, 0, 0);
    }
    __syncthreads();
  }

  // ---- epilogue: bias + store ----
  float bv[4];
  #pragma unroll
  for (int n = 0; n < 4; ++n) bv[n] = bias[F0 + wn * 64 + n * 16 + l15];

  const long rowbase = (long)mi * 128;
  #pragma unroll
  for (int m = 0; m < 4; ++m) {
    #pragma unroll
    for (int j = 0; j < 4; ++j) {
      int wr = wm * 64 + m * 16 + l4 * 4 + j;     // C/D row = (lane>>4)*4 + reg
      float* orow = out + (rowbase + wr) * NF + F0 + wn * 64;
      #pragma unroll
      for (int n = 0; n < 4; ++n)
        orow[n * 16 + l15] = acc[m][n][j] + bv[n];  // C/D col = lane&15
    }
  }
}

extern "C" void kernel_launch(void* const* d_in, const int* in_sizes, int n_in,
                              void* d_out, int out_size, void* d_ws, size_t ws_size,
                              hipStream_t stream) {
  const float* x    = (const float*)d_in[0];
  const float* kern = (const float*)d_in[1];
  const float* bias = (const float*)d_in[2];
  float* out = (float*)d_out;
  unsigned short* bt = (unsigned short*)d_ws;   // 294912 bytes needed

  prep_bt<<<dim3(576), dim3(256), 0, stream>>>(kern, bt);
  conv_main<<<dim3(4096), dim3(256), 0, stream>>>(x, bt, bias, out);
}